// Round 6
// baseline (161.487 us; speedup 1.0000x reference)
//
#include <hip/hip_runtime.h>

// QuantizedWeight dequant:
//   out[g*8+j] = (cb[0, codes[g,0], j] + cb[1, codes[g,1], j]) * scales[g] + zeros[g]
// codes (8.4M,2) i32, codebooks (2,65536,8) f32, scales/zeros (8.4M) f32,
// out flat 8192*8192 f32.
//
// r6: r5 structure (wave-owns-128-groups, LDS staging, pair geometry, dense nt
// stores) + two changes:
//  1. All 8 gathers per super-iteration issued back-to-back into named regs
//     (8 outstanding per wave vs ~3) -> gather latency no longer binding.
//  2. Streams at 1.0 lane-op/group: codes int4/lane; scales+zeros via
//     half-wave split (lanes 0-31 load scales float4, lanes 32-63 zeros float4).
// Per-group VMEM lane-ops: 4 gather + 2 store + 1 stream = 7.0 (floor).

typedef float vf4 __attribute__((ext_vector_type(4)));
typedef int   vi4 __attribute__((ext_vector_type(4)));
typedef int   vi2 __attribute__((ext_vector_type(2)));

__global__ __launch_bounds__(256) void
dequant_kernel(const int* __restrict__ codes,
               const float* __restrict__ cbs,      // [2][65536][8]
               const float* __restrict__ scales,
               const float* __restrict__ zeros,
               float* __restrict__ out,
               int total)                           // groups
{
    const size_t CB1 = (size_t)65536 * 8;           // codebook 1 base (floats)

    // per-wave 2 KB: [0,1024) codes int2[128]; [1024,1536) s[128]; [1536,2048) z[128]
    __shared__ __align__(16) char lds_raw[4 * 2048];
    const int lane = threadIdx.x & 63;
    const int wid  = threadIdx.x >> 6;
    char* wlds = lds_raw + wid * 2048;

    const int  nwaves = (gridDim.x * blockDim.x) >> 6;
    const int  wave   = (blockIdx.x * blockDim.x + threadIdx.x) >> 6;
    const long wstep  = (long)nwaves * 128;

    const vi4* codes4 = (const vi4*)codes;

    const int half = lane & 1;                      // which 16B half of entries
    const int hoff = half * 4;                      // float offset of my half
    const int pidx = lane >> 1;                     // pair index 0..31

    // half-wave split stream source for scales/zeros
    const float* szsrc = (lane < 32) ? scales : zeros;
    const int    sl    = lane & 31;
    char* szdst = wlds + 1024 + ((lane >> 5) << 9) + (sl << 4);

    long gbase = (long)wave * 128;

    if (gbase + 128 <= total) {
        // prologue stream loads
        vi4 pc  = __builtin_nontemporal_load(codes4 + (gbase >> 1) + lane);
        vf4 psz = __builtin_nontemporal_load((const vf4*)(szsrc + gbase) + sl);

        for (;;) {
            const long gcur = gbase;
            gbase += wstep;
            const bool more = (gbase + 128 <= total);

            // stage current (wave-synchronous; in-order DS = no WAR hazard)
            *(vi4*)(wlds + lane * 16) = pc;
            *(vf4*)szdst = psz;

            // prefetch next super-iteration's streams
            if (more) {
                pc  = __builtin_nontemporal_load(codes4 + (gbase >> 1) + lane);
                psz = __builtin_nontemporal_load((const vf4*)(szsrc + gbase) + sl);
            }

            // ---- all 4 code-pair reads (conflict-free, pair-broadcast) ----
            vi2 c0 = *(const vi2*)(wlds + (0 * 32 + pidx) * 8);
            vi2 c1 = *(const vi2*)(wlds + (1 * 32 + pidx) * 8);
            vi2 c2 = *(const vi2*)(wlds + (2 * 32 + pidx) * 8);
            vi2 c3 = *(const vi2*)(wlds + (3 * 32 + pidx) * 8);

            // ---- all 8 gathers back-to-back (8 outstanding per wave) ----
            vf4 e00 = *(const vf4*)(cbs + ((size_t)c0.x << 3) + hoff);
            vf4 e01 = *(const vf4*)(cbs + CB1 + ((size_t)c0.y << 3) + hoff);
            vf4 e10 = *(const vf4*)(cbs + ((size_t)c1.x << 3) + hoff);
            vf4 e11 = *(const vf4*)(cbs + CB1 + ((size_t)c1.y << 3) + hoff);
            vf4 e20 = *(const vf4*)(cbs + ((size_t)c2.x << 3) + hoff);
            vf4 e21 = *(const vf4*)(cbs + CB1 + ((size_t)c2.y << 3) + hoff);
            vf4 e30 = *(const vf4*)(cbs + ((size_t)c3.x << 3) + hoff);
            vf4 e31 = *(const vf4*)(cbs + CB1 + ((size_t)c3.y << 3) + hoff);

            // ---- consume: sz broadcast reads, FMA, dense nt stores ----
            float* ob = out + (size_t)gcur * 8 + pidx * 8 + hoff;

            float s0 = *(const float*)(wlds + 1024 + (0 * 32 + pidx) * 4);
            float z0 = *(const float*)(wlds + 1536 + (0 * 32 + pidx) * 4);
            vf4 r0 = (e00 + e01) * s0 + z0;
            __builtin_nontemporal_store(r0, (vf4*)(ob + 0 * 256));

            float s1 = *(const float*)(wlds + 1024 + (1 * 32 + pidx) * 4);
            float z1 = *(const float*)(wlds + 1536 + (1 * 32 + pidx) * 4);
            vf4 r1 = (e10 + e11) * s1 + z1;
            __builtin_nontemporal_store(r1, (vf4*)(ob + 1 * 256));

            float s2 = *(const float*)(wlds + 1024 + (2 * 32 + pidx) * 4);
            float z2 = *(const float*)(wlds + 1536 + (2 * 32 + pidx) * 4);
            vf4 r2 = (e20 + e21) * s2 + z2;
            __builtin_nontemporal_store(r2, (vf4*)(ob + 2 * 256));

            float s3 = *(const float*)(wlds + 1024 + (3 * 32 + pidx) * 4);
            float z3 = *(const float*)(wlds + 1536 + (3 * 32 + pidx) * 4);
            vf4 r3 = (e30 + e31) * s3 + z3;
            __builtin_nontemporal_store(r3, (vf4*)(ob + 3 * 256));

            if (!more) break;
        }
    }

    // tail: groups not covered by full 128-blocks (none at this size; safety)
    const long total_full = ((long)total >> 7) << 7;
    const int  gtid  = blockIdx.x * blockDim.x + threadIdx.x;
    const long pstep = (long)(gridDim.x * blockDim.x) >> 1;
    for (long g = total_full + (gtid >> 1); g < total; g += pstep) {
        vi2  c = *(const vi2*)(codes + (size_t)2 * g);
        float s = scales[g];
        float z = zeros[g];
        vf4 e0 = *(const vf4*)(cbs + ((size_t)c.x << 3) + hoff);
        vf4 e1 = *(const vf4*)(cbs + CB1 + ((size_t)c.y << 3) + hoff);
        vf4 r  = (e0 + e1) * s + z;
        __builtin_nontemporal_store(r, (vf4*)(out + (size_t)g * 8 + hoff));
    }
}

extern "C" void kernel_launch(void* const* d_in, const int* in_sizes, int n_in,
                              void* d_out, int out_size, void* d_ws, size_t ws_size,
                              hipStream_t stream) {
    const int*   codes     = (const int*)  d_in[0];
    const float* codebooks = (const float*)d_in[1];
    const float* scales    = (const float*)d_in[2];
    const float* zeros     = (const float*)d_in[3];
    float*       out       = (float*)d_out;

    const int total = in_sizes[0] / 2;   // number of groups

    const int threads = 256;
    const int blocks  = 2048;            // 8192 waves x 8 super-iters x 128 = exact
    dequant_kernel<<<blocks, threads, 0, stream>>>(
        codes, codebooks, scales, zeros, out, total);
}

// Round 7
// 151.629 us; speedup vs baseline: 1.0650x; 1.0650x over previous
//
#include <hip/hip_runtime.h>

// QuantizedWeight dequant:
//   out[g*8+j] = (cb[0, codes[g,0], j] + cb[1, codes[g,1], j]) * scales[g] + zeros[g]
// codes (8.4M,2) i32, codebooks (2,65536,8) f32, scales/zeros (8.4M) f32,
// out flat 8192*8192 f32.
//
// r7: repack codebooks to fp16 in d_ws (2 MB), so one lane loads a FULL entry
// with one dwordx4 -> gather lane-ops per group 4 -> 2 (total 7 -> 5).
// Pair lanes (2k,2k+1) split roles: even gathers entry0 (cb0), odd entry1
// (cb1); they exchange the half each needs via 2x shfl_xor(1) (register-only),
// v_pk_add_f16, cvt to f32, FMA, dense 16 B/lane nt store (proven geometry).
// Streams: r6's staging (codes int4/lane, scales/zeros half-wave split float4),
// LDS per wave 2 KB, prefetch depth 1. Fallback to the r6 f32 path if d_ws is
// too small for the fp16 codebook.

typedef float    vf4 __attribute__((ext_vector_type(4)));
typedef int      vi4 __attribute__((ext_vector_type(4)));
typedef int      vi2 __attribute__((ext_vector_type(2)));
typedef _Float16 vh2 __attribute__((ext_vector_type(2)));
typedef _Float16 vh8 __attribute__((ext_vector_type(8)));

// ---------------- repack: f32 codebooks -> fp16 copy in workspace ----------
__global__ __launch_bounds__(256) void
repack_kernel(const float* __restrict__ cbs, _Float16* __restrict__ cb16)
{
    // 2 * 65536 * 8 = 1,048,576 floats; each thread converts 8.
    const int i = blockIdx.x * blockDim.x + threadIdx.x;   // 131072 threads
    const vf4* in4 = (const vf4*)cbs;
    vf4 a = in4[2 * i];
    vf4 b = in4[2 * i + 1];
    vh8 h;
    h[0] = (_Float16)a.x; h[1] = (_Float16)a.y;
    h[2] = (_Float16)a.z; h[3] = (_Float16)a.w;
    h[4] = (_Float16)b.x; h[5] = (_Float16)b.y;
    h[6] = (_Float16)b.z; h[7] = (_Float16)b.w;
    *(vh8*)(cb16 + (size_t)8 * i) = h;
}

// ---------------- main fp16-gather kernel ----------------------------------
__global__ __launch_bounds__(256) void
dequant_fp16(const int* __restrict__ codes,
             const _Float16* __restrict__ cb16,   // [2][65536][8] fp16
             const float* __restrict__ cbs,       // f32 original (tail only)
             const float* __restrict__ scales,
             const float* __restrict__ zeros,
             float* __restrict__ out,
             int total)
{
    __shared__ __align__(16) char lds_raw[4 * 2048];
    const int lane = threadIdx.x & 63;
    const int wid  = threadIdx.x >> 6;
    char* wlds = lds_raw + wid * 2048;   // [0,1024) codes int2[128]
                                         // [1024,1536) s[128]; [1536,2048) z[128]

    const int  nwaves = (gridDim.x * blockDim.x) >> 6;
    const int  wave   = (blockIdx.x * blockDim.x + threadIdx.x) >> 6;
    const long wstep  = (long)nwaves * 128;

    const vi4* codes4 = (const vi4*)codes;

    const int half = lane & 1;            // output half AND entry role
    const int hoff = half * 4;            // float offset of my output half
    const int pidx = lane >> 1;           // pair index 0..31

    const float* szsrc = (lane < 32) ? scales : zeros;
    const int    sl    = lane & 31;
    char* szdst = wlds + 1024 + ((lane >> 5) << 9) + (sl << 4);

    long gbase = (long)wave * 128;

    if (gbase + 128 <= total) {
        vi4 pc  = __builtin_nontemporal_load(codes4 + (gbase >> 1) + lane);
        vf4 psz = __builtin_nontemporal_load((const vf4*)(szsrc + gbase) + sl);

        for (;;) {
            const long gcur = gbase;
            gbase += wstep;
            const bool more = (gbase + 128 <= total);

            // stage current (wave-synchronous)
            *(vi4*)(wlds + lane * 16) = pc;
            *(vf4*)szdst = psz;

            // prefetch next
            if (more) {
                pc  = __builtin_nontemporal_load(codes4 + (gbase >> 1) + lane);
                psz = __builtin_nontemporal_load((const vf4*)(szsrc + gbase) + sl);
            }

            // code reads (pair-broadcast, conflict-free)
            vi2 c0 = *(const vi2*)(wlds + (0 * 32 + pidx) * 8);
            vi2 c1 = *(const vi2*)(wlds + (1 * 32 + pidx) * 8);
            vi2 c2 = *(const vi2*)(wlds + (2 * 32 + pidx) * 8);
            vi2 c3 = *(const vi2*)(wlds + (3 * 32 + pidx) * 8);

            // one full fp16 entry per lane per sub-iter (even: cb0, odd: cb1)
            const int k0 = half ? (c0.y | 65536) : c0.x;
            const int k1 = half ? (c1.y | 65536) : c1.x;
            const int k2 = half ? (c2.y | 65536) : c2.x;
            const int k3 = half ? (c3.y | 65536) : c3.x;
            vi4 e0 = *(const vi4*)(cb16 + ((size_t)(unsigned)k0 << 3));
            vi4 e1 = *(const vi4*)(cb16 + ((size_t)(unsigned)k1 << 3));
            vi4 e2 = *(const vi4*)(cb16 + ((size_t)(unsigned)k2 << 3));
            vi4 e3 = *(const vi4*)(cb16 + ((size_t)(unsigned)k3 << 3));

            float* ob = out + (size_t)gcur * 8 + pidx * 8 + hoff;

            #pragma unroll
            for (int k = 0; k < 4; ++k) {
                vi4 e = (k == 0) ? e0 : (k == 1) ? e1 : (k == 2) ? e2 : e3;
                // exchange: keep dwords 2h,2h+1 of own entry; send 2(1-h)
                int send0 = half ? e.x : e.z;
                int send1 = half ? e.y : e.w;
                int own0  = half ? e.z : e.x;
                int own1  = half ? e.w : e.y;
                int recv0 = __shfl_xor(send0, 1);
                int recv1 = __shfl_xor(send1, 1);
                vh2 s0 = __builtin_bit_cast(vh2, own0) + __builtin_bit_cast(vh2, recv0);
                vh2 s1 = __builtin_bit_cast(vh2, own1) + __builtin_bit_cast(vh2, recv1);

                float s = *(const float*)(wlds + 1024 + (k * 32 + pidx) * 4);
                float z = *(const float*)(wlds + 1536 + (k * 32 + pidx) * 4);
                vf4 r;
                r.x = (float)s0.x * s + z;
                r.y = (float)s0.y * s + z;
                r.z = (float)s1.x * s + z;
                r.w = (float)s1.y * s + z;
                __builtin_nontemporal_store(r, (vf4*)(ob + k * 256));
            }
            if (!more) break;
        }
    }

    // tail (none at this size; f32 path for safety)
    const size_t CB1 = (size_t)65536 * 8;
    const long total_full = ((long)total >> 7) << 7;
    const int  gtid  = blockIdx.x * blockDim.x + threadIdx.x;
    const long pstep = (long)(gridDim.x * blockDim.x) >> 1;
    for (long g = total_full + (gtid >> 1); g < total; g += pstep) {
        vi2  c = *(const vi2*)(codes + (size_t)2 * g);
        float s = scales[g];
        float z = zeros[g];
        vf4 a0 = *(const vf4*)(cbs + ((size_t)c.x << 3) + hoff);
        vf4 a1 = *(const vf4*)(cbs + CB1 + ((size_t)c.y << 3) + hoff);
        vf4 r  = (a0 + a1) * s + z;
        __builtin_nontemporal_store(r, (vf4*)(out + (size_t)g * 8 + hoff));
    }
}

// ---------------- fallback: r6 f32 kernel (ws too small) -------------------
__global__ __launch_bounds__(256) void
dequant_f32(const int* __restrict__ codes,
            const float* __restrict__ cbs,
            const float* __restrict__ scales,
            const float* __restrict__ zeros,
            float* __restrict__ out,
            int total)
{
    const size_t CB1 = (size_t)65536 * 8;
    __shared__ __align__(16) char lds_raw[4 * 2048];
    const int lane = threadIdx.x & 63;
    const int wid  = threadIdx.x >> 6;
    char* wlds = lds_raw + wid * 2048;
    const int  nwaves = (gridDim.x * blockDim.x) >> 6;
    const int  wave   = (blockIdx.x * blockDim.x + threadIdx.x) >> 6;
    const long wstep  = (long)nwaves * 128;
    const vi4* codes4 = (const vi4*)codes;
    const int half = lane & 1;
    const int hoff = half * 4;
    const int pidx = lane >> 1;
    const float* szsrc = (lane < 32) ? scales : zeros;
    const int    sl    = lane & 31;
    char* szdst = wlds + 1024 + ((lane >> 5) << 9) + (sl << 4);
    long gbase = (long)wave * 128;
    if (gbase + 128 <= total) {
        vi4 pc  = __builtin_nontemporal_load(codes4 + (gbase >> 1) + lane);
        vf4 psz = __builtin_nontemporal_load((const vf4*)(szsrc + gbase) + sl);
        for (;;) {
            const long gcur = gbase;
            gbase += wstep;
            const bool more = (gbase + 128 <= total);
            *(vi4*)(wlds + lane * 16) = pc;
            *(vf4*)szdst = psz;
            if (more) {
                pc  = __builtin_nontemporal_load(codes4 + (gbase >> 1) + lane);
                psz = __builtin_nontemporal_load((const vf4*)(szsrc + gbase) + sl);
            }
            vi2 c0 = *(const vi2*)(wlds + (0 * 32 + pidx) * 8);
            vi2 c1 = *(const vi2*)(wlds + (1 * 32 + pidx) * 8);
            vi2 c2 = *(const vi2*)(wlds + (2 * 32 + pidx) * 8);
            vi2 c3 = *(const vi2*)(wlds + (3 * 32 + pidx) * 8);
            vf4 e00 = *(const vf4*)(cbs + ((size_t)c0.x << 3) + hoff);
            vf4 e01 = *(const vf4*)(cbs + CB1 + ((size_t)c0.y << 3) + hoff);
            vf4 e10 = *(const vf4*)(cbs + ((size_t)c1.x << 3) + hoff);
            vf4 e11 = *(const vf4*)(cbs + CB1 + ((size_t)c1.y << 3) + hoff);
            vf4 e20 = *(const vf4*)(cbs + ((size_t)c2.x << 3) + hoff);
            vf4 e21 = *(const vf4*)(cbs + CB1 + ((size_t)c2.y << 3) + hoff);
            vf4 e30 = *(const vf4*)(cbs + ((size_t)c3.x << 3) + hoff);
            vf4 e31 = *(const vf4*)(cbs + CB1 + ((size_t)c3.y << 3) + hoff);
            float* ob = out + (size_t)gcur * 8 + pidx * 8 + hoff;
            float s0 = *(const float*)(wlds + 1024 + (0 * 32 + pidx) * 4);
            float z0 = *(const float*)(wlds + 1536 + (0 * 32 + pidx) * 4);
            __builtin_nontemporal_store((e00 + e01) * s0 + z0, (vf4*)(ob + 0 * 256));
            float s1 = *(const float*)(wlds + 1024 + (1 * 32 + pidx) * 4);
            float z1 = *(const float*)(wlds + 1536 + (1 * 32 + pidx) * 4);
            __builtin_nontemporal_store((e10 + e11) * s1 + z1, (vf4*)(ob + 1 * 256));
            float s2 = *(const float*)(wlds + 1024 + (2 * 32 + pidx) * 4);
            float z2 = *(const float*)(wlds + 1536 + (2 * 32 + pidx) * 4);
            __builtin_nontemporal_store((e20 + e21) * s2 + z2, (vf4*)(ob + 2 * 256));
            float s3 = *(const float*)(wlds + 1024 + (3 * 32 + pidx) * 4);
            float z3 = *(const float*)(wlds + 1536 + (3 * 32 + pidx) * 4);
            __builtin_nontemporal_store((e30 + e31) * s3 + z3, (vf4*)(ob + 3 * 256));
            if (!more) break;
        }
    }
    const long total_full = ((long)total >> 7) << 7;
    const int  gtid  = blockIdx.x * blockDim.x + threadIdx.x;
    const long pstep = (long)(gridDim.x * blockDim.x) >> 1;
    for (long g = total_full + (gtid >> 1); g < total; g += pstep) {
        vi2  c = *(const vi2*)(codes + (size_t)2 * g);
        float s = scales[g];
        float z = zeros[g];
        vf4 a0 = *(const vf4*)(cbs + ((size_t)c.x << 3) + hoff);
        vf4 a1 = *(const vf4*)(cbs + CB1 + ((size_t)c.y << 3) + hoff);
        vf4 r  = (a0 + a1) * s + z;
        __builtin_nontemporal_store(r, (vf4*)(out + (size_t)g * 8 + hoff));
    }
}

extern "C" void kernel_launch(void* const* d_in, const int* in_sizes, int n_in,
                              void* d_out, int out_size, void* d_ws, size_t ws_size,
                              hipStream_t stream) {
    const int*   codes     = (const int*)  d_in[0];
    const float* codebooks = (const float*)d_in[1];
    const float* scales    = (const float*)d_in[2];
    const float* zeros     = (const float*)d_in[3];
    float*       out       = (float*)d_out;

    const int total = in_sizes[0] / 2;           // number of groups
    const size_t cb16_bytes = (size_t)2 * 65536 * 8 * sizeof(_Float16); // 2 MB

    if (ws_size >= cb16_bytes) {
        _Float16* cb16 = (_Float16*)d_ws;
        repack_kernel<<<512, 256, 0, stream>>>(codebooks, cb16);
        dequant_fp16<<<2048, 256, 0, stream>>>(
            codes, cb16, codebooks, scales, zeros, out, total);
    } else {
        dequant_f32<<<2048, 256, 0, stream>>>(
            codes, codebooks, scales, zeros, out, total);
    }
}

// Round 8
// 133.515 us; speedup vs baseline: 1.2095x; 1.1357x over previous
//
#include <hip/hip_runtime.h>

// QuantizedWeight dequant:
//   out[g*8+j] = (cb[0, codes[g,0], j] + cb[1, codes[g,1], j]) * scales[g] + zeros[g]
//
// r8: test the gather latency x concurrency hypothesis properly.
//   - wave owns 256 consecutive groups per super-iteration
//   - 8 gather instructions issued back-to-back into 8 NAMED vi4 regs (32 VGPR
//     live) before any consume -> true 8-deep MLP per wave (r6's attempt was
//     defeated by regalloc at 44 VGPR)
//   - __launch_bounds__(256, 4): cap 128 VGPR, 4 waves/SIMD = 16 waves/CU
//   - everything proven kept: fp16 codebook repack in d_ws (entry = one
//     dwordx4/lane), pair-lane role split + shfl_xor exchange, LDS staging of
//     codes/scales/zeros, dense 16 B/lane nt stores, prefetch depth 1.

typedef float    vf4 __attribute__((ext_vector_type(4)));
typedef int      vi4 __attribute__((ext_vector_type(4)));
typedef int      vi2 __attribute__((ext_vector_type(2)));
typedef _Float16 vh2 __attribute__((ext_vector_type(2)));
typedef _Float16 vh8 __attribute__((ext_vector_type(8)));

// ---------------- repack: f32 codebooks -> fp16 copy in workspace ----------
__global__ __launch_bounds__(256) void
repack_kernel(const float* __restrict__ cbs, _Float16* __restrict__ cb16)
{
    const int i = blockIdx.x * blockDim.x + threadIdx.x;   // 131072 threads
    const vf4* in4 = (const vf4*)cbs;
    vf4 a = in4[2 * i];
    vf4 b = in4[2 * i + 1];
    vh8 h;
    h[0] = (_Float16)a.x; h[1] = (_Float16)a.y;
    h[2] = (_Float16)a.z; h[3] = (_Float16)a.w;
    h[4] = (_Float16)b.x; h[5] = (_Float16)b.y;
    h[6] = (_Float16)b.z; h[7] = (_Float16)b.w;
    *(vh8*)(cb16 + (size_t)8 * i) = h;
}

// ---------------- main fp16-gather kernel, 8-deep MLP -----------------------
__global__ __launch_bounds__(256, 4) void
dequant_fp16(const int* __restrict__ codes,
             const _Float16* __restrict__ cb16,   // [2][65536][8] fp16
             const float* __restrict__ cbs,       // f32 original (tail only)
             const float* __restrict__ scales,
             const float* __restrict__ zeros,
             float* __restrict__ out,
             int total)
{
    // per-wave 4 KB: [0,2048) codes int2[256]; [2048,3072) s[256]; [3072,4096) z[256]
    __shared__ __align__(16) char lds_raw[4 * 4096];
    const int lane = threadIdx.x & 63;
    const int wid  = threadIdx.x >> 6;
    char* wlds = lds_raw + wid * 4096;

    const int  nwaves = (gridDim.x * blockDim.x) >> 6;
    const int  wave   = (blockIdx.x * blockDim.x + threadIdx.x) >> 6;
    const long wstep  = (long)nwaves * 256;

    const vi4* codes4 = (const vi4*)codes;

    const int half = lane & 1;            // output half AND entry role
    const int hoff = half * 4;            // float offset of my output half
    const int pidx = lane >> 1;           // pair index 0..31

    const float* szsrc = (lane < 32) ? scales : zeros;
    const int    sl    = lane & 31;
    char* szdst = wlds + 2048 + ((lane >> 5) << 10) + (sl << 4);

    long gbase = (long)wave * 256;

    if (gbase + 256 <= total) {
        // prologue stream loads (cover 256 groups)
        vi4 pc0  = __builtin_nontemporal_load(codes4 + (gbase >> 1) + lane);
        vi4 pc1  = __builtin_nontemporal_load(codes4 + (gbase >> 1) + 64 + lane);
        vf4 psz0 = __builtin_nontemporal_load((const vf4*)(szsrc + gbase) + sl);
        vf4 psz1 = __builtin_nontemporal_load((const vf4*)(szsrc + gbase) + 32 + sl);

        for (;;) {
            const long gcur = gbase;
            gbase += wstep;
            const bool more = (gbase + 256 <= total);

            // stage current super-iteration (wave-synchronous, in-order DS)
            *(vi4*)(wlds + lane * 16)        = pc0;
            *(vi4*)(wlds + 1024 + lane * 16) = pc1;
            *(vf4*)szdst                     = psz0;
            *(vf4*)(szdst + 512)             = psz1;

            // prefetch next super-iteration's streams
            if (more) {
                pc0  = __builtin_nontemporal_load(codes4 + (gbase >> 1) + lane);
                pc1  = __builtin_nontemporal_load(codes4 + (gbase >> 1) + 64 + lane);
                psz0 = __builtin_nontemporal_load((const vf4*)(szsrc + gbase) + sl);
                psz1 = __builtin_nontemporal_load((const vf4*)(szsrc + gbase) + 32 + sl);
            }

            // ---- 8 code-pair reads (pair-broadcast, 2-way = free) ----
            vi2 c0 = *(const vi2*)(wlds + (0 * 32 + pidx) * 8);
            vi2 c1 = *(const vi2*)(wlds + (1 * 32 + pidx) * 8);
            vi2 c2 = *(const vi2*)(wlds + (2 * 32 + pidx) * 8);
            vi2 c3 = *(const vi2*)(wlds + (3 * 32 + pidx) * 8);
            vi2 c4 = *(const vi2*)(wlds + (4 * 32 + pidx) * 8);
            vi2 c5 = *(const vi2*)(wlds + (5 * 32 + pidx) * 8);
            vi2 c6 = *(const vi2*)(wlds + (6 * 32 + pidx) * 8);
            vi2 c7 = *(const vi2*)(wlds + (7 * 32 + pidx) * 8);

            // ---- 8 gathers back-to-back into named regs (8-deep MLP) ----
            const int k0 = half ? (c0.y | 65536) : c0.x;
            const int k1 = half ? (c1.y | 65536) : c1.x;
            const int k2 = half ? (c2.y | 65536) : c2.x;
            const int k3 = half ? (c3.y | 65536) : c3.x;
            const int k4 = half ? (c4.y | 65536) : c4.x;
            const int k5 = half ? (c5.y | 65536) : c5.x;
            const int k6 = half ? (c6.y | 65536) : c6.x;
            const int k7 = half ? (c7.y | 65536) : c7.x;
            vi4 e0 = *(const vi4*)(cb16 + ((size_t)(unsigned)k0 << 3));
            vi4 e1 = *(const vi4*)(cb16 + ((size_t)(unsigned)k1 << 3));
            vi4 e2 = *(const vi4*)(cb16 + ((size_t)(unsigned)k2 << 3));
            vi4 e3 = *(const vi4*)(cb16 + ((size_t)(unsigned)k3 << 3));
            vi4 e4 = *(const vi4*)(cb16 + ((size_t)(unsigned)k4 << 3));
            vi4 e5 = *(const vi4*)(cb16 + ((size_t)(unsigned)k5 << 3));
            vi4 e6 = *(const vi4*)(cb16 + ((size_t)(unsigned)k6 << 3));
            vi4 e7 = *(const vi4*)(cb16 + ((size_t)(unsigned)k7 << 3));

            float* ob = out + (size_t)gcur * 8 + pidx * 8 + hoff;

            // ---- consume in issue order (staged vmcnt waits) ----
            #pragma unroll
            for (int k = 0; k < 8; ++k) {
                vi4 e = (k == 0) ? e0 : (k == 1) ? e1 : (k == 2) ? e2 :
                        (k == 3) ? e3 : (k == 4) ? e4 : (k == 5) ? e5 :
                        (k == 6) ? e6 : e7;
                // exchange: keep my output-half dwords of own entry, swap the rest
                int send0 = half ? e.x : e.z;
                int send1 = half ? e.y : e.w;
                int own0  = half ? e.z : e.x;
                int own1  = half ? e.w : e.y;
                int recv0 = __shfl_xor(send0, 1);
                int recv1 = __shfl_xor(send1, 1);
                vh2 s0 = __builtin_bit_cast(vh2, own0) + __builtin_bit_cast(vh2, recv0);
                vh2 s1 = __builtin_bit_cast(vh2, own1) + __builtin_bit_cast(vh2, recv1);

                float s = *(const float*)(wlds + 2048 + (k * 32 + pidx) * 4);
                float z = *(const float*)(wlds + 3072 + (k * 32 + pidx) * 4);
                vf4 r;
                r.x = (float)s0.x * s + z;
                r.y = (float)s0.y * s + z;
                r.z = (float)s1.x * s + z;
                r.w = (float)s1.y * s + z;
                __builtin_nontemporal_store(r, (vf4*)(ob + k * 256));
            }
            if (!more) break;
        }
    }

    // tail: groups not covered by full 256-blocks (none at this size; safety)
    const size_t CB1 = (size_t)65536 * 8;
    const long total_full = ((long)total >> 8) << 8;
    const int  gtid  = blockIdx.x * blockDim.x + threadIdx.x;
    const long pstep = (long)(gridDim.x * blockDim.x) >> 1;
    for (long g = total_full + (gtid >> 1); g < total; g += pstep) {
        vi2  c = *(const vi2*)(codes + (size_t)2 * g);
        float s = scales[g];
        float z = zeros[g];
        vf4 a0 = *(const vf4*)(cbs + ((size_t)c.x << 3) + hoff);
        vf4 a1 = *(const vf4*)(cbs + CB1 + ((size_t)c.y << 3) + hoff);
        vf4 r  = (a0 + a1) * s + z;
        __builtin_nontemporal_store(r, (vf4*)(out + (size_t)g * 8 + hoff));
    }
}

// ---------------- fallback (ws too small): r4 pair kernel -------------------
__global__ __launch_bounds__(256) void
dequant_f32(const int* __restrict__ codes,
            const float* __restrict__ cbs,
            const float* __restrict__ scales,
            const float* __restrict__ zeros,
            float* __restrict__ out,
            int total)
{
    const size_t CB1 = (size_t)65536 * 8;
    const vi2* codes2 = (const vi2*)codes;
    const int tid   = blockIdx.x * blockDim.x + threadIdx.x;
    const int half  = tid & 1;
    const int hoff  = half * 4;
    const int gstep = (gridDim.x * blockDim.x) >> 1;
    for (int g = tid >> 1; g < total; g += gstep) {
        vi2  c = __builtin_nontemporal_load(codes2 + g);
        float s = __builtin_nontemporal_load(scales + g);
        float z = __builtin_nontemporal_load(zeros + g);
        vf4 e0 = *(const vf4*)(cbs + ((size_t)c.x << 3) + hoff);
        vf4 e1 = *(const vf4*)(cbs + CB1 + ((size_t)c.y << 3) + hoff);
        vf4 r  = (e0 + e1) * s + z;
        __builtin_nontemporal_store(r, (vf4*)(out + (size_t)g * 8 + hoff));
    }
}

extern "C" void kernel_launch(void* const* d_in, const int* in_sizes, int n_in,
                              void* d_out, int out_size, void* d_ws, size_t ws_size,
                              hipStream_t stream) {
    const int*   codes     = (const int*)  d_in[0];
    const float* codebooks = (const float*)d_in[1];
    const float* scales    = (const float*)d_in[2];
    const float* zeros     = (const float*)d_in[3];
    float*       out       = (float*)d_out;

    const int total = in_sizes[0] / 2;           // number of groups
    const size_t cb16_bytes = (size_t)2 * 65536 * 8 * sizeof(_Float16); // 2 MB

    if (ws_size >= cb16_bytes) {
        _Float16* cb16 = (_Float16*)d_ws;
        repack_kernel<<<512, 256, 0, stream>>>(codebooks, cb16);
        dequant_fp16<<<2048, 256, 0, stream>>>(
            codes, cb16, codebooks, scales, zeros, out, total);
    } else {
        dequant_f32<<<2048, 256, 0, stream>>>(
            codes, codebooks, scales, zeros, out, total);
    }
}